// Round 11
// baseline (159.299 us; speedup 1.0000x reference)
//
#include <hip/hip_runtime.h>
#include <hip/hip_bf16.h>

namespace {

constexpr int Bn = 2, Sn = 2048, Hn = 16, Dn = 128;
constexpr int QBLK = 128;   // queries per tile (4 waves x 32q)
constexpr int KVBLK = 32;   // image chunk granularity (32 keys / 8 KB)
constexpr int RS = Hn * Dn; // 2048 floats
constexpr float QSCALE = 0.08838834764831845f * 1.4426950408889634f; // 1/sqrt(D)*log2(e)

// bf16 K/V images, pre-swizzled to the exact LDS chunk layout.
constexpr size_t IMG_BYTES = (size_t)Bn * Hn * 64 * 8192;   // 16 MB
constexpr size_t WS_NEED   = 2 * IMG_BYTES;                 // 32 MB

typedef __bf16 bf16x8 __attribute__((ext_vector_type(8)));
typedef float  f32x16 __attribute__((ext_vector_type(16)));

__device__ __forceinline__ f32x16 mfma32(bf16x8 a, bf16x8 b, f32x16 c) {
  return __builtin_amdgcn_mfma_f32_32x32x16_bf16(a, b, c, 0, 0, 0);
}
__device__ __forceinline__ unsigned pack2(float a, float b) {
  union { __bf16 h[2]; unsigned u; } r;
  r.h[0] = (__bf16)a; r.h[1] = (__bf16)b;
  return r.u;
}
// lane<->lane^32 exchange on the VALU pipe (T12 primitive).
__device__ __forceinline__ float pair_max(float x, int hi) {
  auto r = __builtin_amdgcn_permlane32_swap(__float_as_uint(x), __float_as_uint(x), false, false);
  const float sw = __uint_as_float(hi ? r[0] : r[1]);
  return fmaxf(x, sw);
}
__device__ __forceinline__ float pair_sum(float x, int hi) {
  auto r = __builtin_amdgcn_permlane32_swap(__float_as_uint(x), __float_as_uint(x), false, false);
  const float sw = __uint_as_float(hi ? r[0] : r[1]);
  return x + sw;
}
__device__ __forceinline__ float lane_bcast(int row, float v) {
  return __uint_as_float(__builtin_amdgcn_ds_bpermute(row * 4, __float_as_uint(v)));
}

// async 16B global->LDS DMA (linear dest: uniform lds base + lane*16)
__device__ __forceinline__ void cp16(const char* g, char* l) {
  __builtin_amdgcn_global_load_lds(
      (const __attribute__((address_space(1))) void*)g,
      (__attribute__((address_space(3))) void*)l, 16, 0, 0);
}

// full barrier for a 4-wave block: DMA'd LDS + ds ops visible.
__device__ __forceinline__ void dma_barrier() {
  __builtin_amdgcn_sched_barrier(0);
  asm volatile("s_waitcnt vmcnt(0) lgkmcnt(0)" ::: "memory");
  __builtin_amdgcn_s_barrier();
  __builtin_amdgcn_sched_barrier(0);
}

// ============================================================================
// Pre-pass: fp32 K/V -> bf16 images in the EXACT swizzled LDS chunk layout.
// (verbatim, verified R6-R10)
// ============================================================================
__global__ __launch_bounds__(256)
void prep_kv(const float* __restrict__ K, const float* __restrict__ V,
             __bf16* __restrict__ KI, __bf16* __restrict__ VI)
{
  const int gid  = (int)blockIdx.x * 256 + (int)threadIdx.x; // 0..2M
  const int half = gid >> 20;              // 0=K, 1=V
  const int id   = gid & ((1 << 20) - 1);  // 0..1M
  const int chunk = id >> 9;               // 0..2047
  const int rem   = id & 511;
  const int bh = chunk >> 6, c = chunk & 63;
  const int b = bh >> 4, h = bh & 15;
  if (half == 0) {
    const int key = rem >> 4, dblk = rem & 15;
    const float* src = K + ((size_t)b * Sn + (size_t)c * 32 + key) * RS + h * Dn + dblk * 8;
    float4 a  = *(const float4*)src;
    float4 c2 = *(const float4*)(src + 4);
    bf16x8 f;
    f[0] = (__bf16)a.x;  f[1] = (__bf16)a.y;  f[2] = (__bf16)a.z;  f[3] = (__bf16)a.w;
    f[4] = (__bf16)c2.x; f[5] = (__bf16)c2.y; f[6] = (__bf16)c2.z; f[7] = (__bf16)c2.w;
    char* dst = (char*)KI + (size_t)chunk * 8192 + ((key * 256 + dblk * 16) ^ ((key & 7) << 4));
    *(bf16x8*)dst = f;
  } else {
    const int d = rem >> 2, koct = rem & 3;
    const float* src = V + ((size_t)b * Sn + (size_t)c * 32 + koct * 8) * RS + h * Dn + d;
    bf16x8 f;
#pragma unroll
    for (int j = 0; j < 8; ++j) f[j] = (__bf16)src[(size_t)j * RS];
    const int off = (d * 64 + koct * 16) ^ ((d & 3) << 4) ^ (((d >> 3) & 1) << 6);
    *(bf16x8*)((char*)VI + (size_t)chunk * 8192 + off) = f;
  }
}

// ============================================================================
// R11 main kernel: 512 blocks x 256 THREADS (4 waves). Session model (r0-r10
// reconciliation): true reg allocation ~190/wave (128 arch + ~64 unified-file
// acc) -> 2 waves/SIMD -> 8 wave-slots/CU. An 8-wave (512-thread) block can
// therefore NEVER co-reside with another: every prior "2 blocks/CU" schedule
// silently ran 1 block/CU (occupancy 18-21% = 8 waves). 4-wave blocks are the
// unlock: TWO independent blocks = two independent barrier domains per CU.
// Block = one 128q tile, 4 q-waves x 32q, SINGLE key-group (superstep = one
// 32-key chunk, all waves) -> no end-of-tile merge at all. K ring-4 + V
// ring-4 = 64 KB/block -> 2 blocks/CU by LDS as well. Inner code = verified
// R6 path (resident qf, stn S-pipeline, T13 defer-max, permlane repack,
// image DMA). Dispatch pairing (s, s+32): same head, qt 15-i <-> i ->
// per-CU work uniform at 68 chunks if the dispatcher co-locates them.
// ============================================================================
__global__ __launch_bounds__(256)
void fa_fwd_w4(const float* __restrict__ Q, const __bf16* __restrict__ KI,
               const __bf16* __restrict__ VI, float* __restrict__ O)
{
  __shared__ __align__(16) __bf16 Klds[4][4096]; // 32 KB, slot = chunk & 3
  __shared__ __align__(16) __bf16 Vt[4][4096];   // 32 KB, slot = chunk & 3

  const int tid  = threadIdx.x;
  const int lane = tid & 63;
  const int wave = tid >> 6;    // 0..3 = q-wave
  const int col  = lane & 31;
  const int hi   = lane >> 5;

  // mapping: 64 blocks per XCD = 4 heads x 16 tiles. First 32 (s<32) take the
  // LONG tiles (qt 15..8), second 32 the short ones (qt 7..0); co-resident
  // pair (s, s+32) = same head, complementary qt -> 68 chunks per CU.
  const int xcd = (int)blockIdx.x & 7;
  const int s   = (int)blockIdx.x >> 3;     // 0..63
  const int i   = s & 7;
  const int h2  = (s & 31) >> 3;            // 0..3
  const int qt  = (s < 32) ? (15 - i) : i;
  const int hidx = xcd * 4 + h2;            // 0..31
  const int b    = hidx >> 4, h = hidx & 15;
  const int q0w  = qt * QBLK + wave * 32;
  const int T    = 4 * (qt + 1);            // 32-key chunks
  const size_t base = ((size_t)b * Sn) * RS + (size_t)h * Dn;

  const char* KIc = (const char*)KI + (size_t)hidx * 64 * 8192;
  const char* VIc = (const char*)VI + (size_t)hidx * 64 * 8192;

  // staging: each wave DMAs its 2 KB quarter of the 8 KB chunk (2x cp16 each
  // for K and V). LDS dest is wave-uniform base (+ implicit lane*16).
  auto stageK = [&](int c) {
    const char* g = KIc + (size_t)c * 8192 + wave * 2048 + lane * 16;
    char* l = (char*)&Klds[c & 3][0] + wave * 2048;
    cp16(g, l);
    cp16(g + 1024, l + 1024);
  };
  auto stageV = [&](int c) {
    const char* g = VIc + (size_t)c * 8192 + wave * 2048 + lane * 16;
    char* l = (char*)&Vt[c & 3][0] + wave * 2048;
    cp16(g, l);
    cp16(g + 1024, l + 1024);
  };

  const int cswz = (col & 7) << 4;
  const int vswz = ((col & 3) << 4) ^ (((col >> 3) & 1) << 6);

  // ---- Q fragments, scaled (resident) ----
  bf16x8 qf[8];
  {
    const float* qp = Q + base + (size_t)(q0w + col) * RS + hi * 8;
#pragma unroll
    for (int kk = 0; kk < 8; ++kk) {
      float4 a = *(const float4*)(qp + kk * 16);
      float4 c2 = *(const float4*)(qp + kk * 16 + 4);
      bf16x8 f;
      f[0] = (__bf16)(a.x * QSCALE);  f[1] = (__bf16)(a.y * QSCALE);
      f[2] = (__bf16)(a.z * QSCALE);  f[3] = (__bf16)(a.w * QSCALE);
      f[4] = (__bf16)(c2.x * QSCALE); f[5] = (__bf16)(c2.y * QSCALE);
      f[6] = (__bf16)(c2.z * QSCALE); f[7] = (__bf16)(c2.w * QSCALE);
      qf[kk] = f;
    }
  }

  f32x16 o0 = {}, o1 = {}, o2 = {}, o3 = {};
  float m = -1e30f, l = 0.f;

  // ---- prologue: DMA K0,V0,K1; wait; QK(0) ----
  stageK(0);
  stageV(0);
  stageK(1);
  dma_barrier();

  f32x16 st_cur = {};
  {
    const char* kb = (const char*)&Klds[0][0];
    __builtin_amdgcn_s_setprio(1);
#pragma unroll
    for (int kk = 0; kk < 8; ++kk) {
      bf16x8 ka = *(const bf16x8*)(kb + ((col * 256 + kk * 32 + hi * 16) ^ cswz));
      st_cur = mfma32(ka, qf[kk], st_cur);
    }
    __builtin_amdgcn_s_setprio(0);
  }
  // no fence needed: iter-0 DMAs write slots 2 (K) and 1 (V); QK(0) reads
  // K slot 0; slot 0 is first rewritten by stage K(4) at iter 2 (2 barriers).

#pragma unroll 1
  for (int t = 0; t < T; ++t) {
    // ---- issue next DMAs first: K(t+2) -> slot (t+2)&3 (reads drained at
    // barrier t-3); V(t+1) -> slot (t+1)&3 (read next iter) ----
    if (t + 2 < T) stageK(t + 2);
    if (t + 1 < T) stageV(t + 1);

    // ---- QK(t+1) on the MFMA pipe (S-pipeline) ----
    f32x16 stn = {};
    if (t + 1 < T && 32 * (t + 1) <= q0w + 31) {
      const char* kb = (const char*)&Klds[(t + 1) & 3][0];
      __builtin_amdgcn_s_setprio(1);
#pragma unroll
      for (int kk = 0; kk < 8; ++kk) {
        bf16x8 ka = *(const bf16x8*)(kb + ((col * 256 + kk * 32 + hi * 16) ^ cswz));
        stn = mfma32(ka, qf[kk], stn);
      }
      __builtin_amdgcn_s_setprio(0);
    }

    // ---- finish chunk t: mask, softmax, repack, PV ----
    const int kv0 = 32 * t;
    if (kv0 <= q0w + 31) {
      if (kv0 + KVBLK - 1 > q0w) {
        const int qk = q0w + col - kv0;
#pragma unroll
        for (int r = 0; r < 16; ++r) {
          const int krow = (r & 3) + 8 * (r >> 2) + 4 * hi;
          st_cur[r] = (krow <= qk) ? st_cur[r] : -1e30f;
        }
      }

      float t8[8];
#pragma unroll
      for (int r = 0; r < 8; ++r) t8[r] = fmaxf(st_cur[r], st_cur[r + 8]);
#pragma unroll
      for (int r = 0; r < 4; ++r) t8[r] = fmaxf(t8[r], t8[r + 4]);
      const float pmax = pair_max(fmaxf(fmaxf(t8[0], t8[1]), fmaxf(t8[2], t8[3])), hi);

      if (!__all(pmax <= m + 11.0f)) {   // T13 defer-max
        const float mnew = fmaxf(m, pmax);
        const float al = __builtin_amdgcn_exp2f(m - mnew);
        m = mnew;
        l *= al;
#pragma unroll
        for (int r = 0; r < 16; ++r) {
          const int row = (r & 3) + 8 * (r >> 2) + 4 * hi;
          const float ar = lane_bcast(row, al);
          o0[r] *= ar; o1[r] *= ar; o2[r] *= ar; o3[r] *= ar;
        }
      }

      float s4[4] = {0.f, 0.f, 0.f, 0.f};
#pragma unroll
      for (int r = 0; r < 16; ++r) {
        st_cur[r] = __builtin_amdgcn_exp2f(st_cur[r] - m);
        s4[r & 3] += st_cur[r];
      }
      l += pair_sum((s4[0] + s4[1]) + (s4[2] + s4[3]), hi);

      // P -> A-fragments via 4 permlane32_swap
      unsigned cw[8];
#pragma unroll
      for (int ii = 0; ii < 8; ++ii) cw[ii] = pack2(st_cur[2 * ii], st_cur[2 * ii + 1]);
      union { unsigned u[4]; bf16x8 v; } pa0, pa1;
      {
        auto s02 = __builtin_amdgcn_permlane32_swap(cw[0], cw[2], false, false);
        auto s13 = __builtin_amdgcn_permlane32_swap(cw[1], cw[3], false, false);
        auto s46 = __builtin_amdgcn_permlane32_swap(cw[4], cw[6], false, false);
        auto s57 = __builtin_amdgcn_permlane32_swap(cw[5], cw[7], false, false);
        pa0.u[0] = s02[0]; pa0.u[2] = s02[1];
        pa0.u[1] = s13[0]; pa0.u[3] = s13[1];
        pa1.u[0] = s46[0]; pa1.u[2] = s46[1];
        pa1.u[1] = s57[0]; pa1.u[3] = s57[1];
      }

      const char* vb = (const char*)&Vt[t & 3][0];
      __builtin_amdgcn_s_setprio(1);
#pragma unroll
      for (int ks = 0; ks < 2; ++ks) {
        const bf16x8 pa = ks ? pa1.v : pa0.v;
#define PV_STEP(ovar, dt) { \
        bf16x8 vf = *(const bf16x8*)(vb + ((((dt)*32 + col) * 64 + ks * 32 + hi * 16) ^ vswz)); \
        ovar = mfma32(pa, vf, ovar); }
        PV_STEP(o0, 0) PV_STEP(o1, 1) PV_STEP(o2, 2) PV_STEP(o3, 3)
#undef PV_STEP
      }
      __builtin_amdgcn_s_setprio(0);
    }
    dma_barrier();
    st_cur = stn;
  }

  // ---- epilogue: single group -> no merge; store directly ----
  const float linv = 1.0f / l;
#pragma unroll
  for (int r = 0; r < 16; ++r) {
    const int row = (r & 3) + 8 * (r >> 2) + 4 * hi;
    const float lr = lane_bcast(row, linv);
    float* op = O + base + (size_t)(q0w + row) * RS + col;
    op[0]  = o0[r] * lr;
    op[32] = o1[r] * lr;
    op[64] = o2[r] * lr;
    op[96] = o3[r] * lr;
  }
}

} // namespace

extern "C" void kernel_launch(void* const* d_in, const int* /*in_sizes*/, int /*n_in*/,
                              void* d_out, int /*out_size*/, void* d_ws, size_t /*ws_size*/,
                              hipStream_t stream) {
  const float* q = (const float*)d_in[0];
  const float* k = (const float*)d_in[1];
  const float* v = (const float*)d_in[2];
  float* o = (float*)d_out;
  // ws >= 98 MB proven on this harness (R10 ran the split path); images = 32 MB.
  __bf16* ki = (__bf16*)d_ws;
  __bf16* vi = (__bf16*)((char*)d_ws + IMG_BYTES);
  hipLaunchKernelGGL(prep_kv, dim3(8192), dim3(256), 0, stream, k, v, ki, vi);
  hipLaunchKernelGGL(fa_fwd_w4, dim3(512), dim3(256), 0, stream, q, ki, vi, o);
}

// Round 13
// 97.547 us; speedup vs baseline: 1.6330x; 1.6330x over previous
//
#include <hip/hip_runtime.h>
#include <hip/hip_bf16.h>

namespace {

constexpr int Bn = 2, Sn = 2048, Hn = 16, Dn = 128;
constexpr int QBLK = 128;   // 4 q-waves x 32 queries, 2 key-groups
constexpr int KVBLK = 32;   // image chunk granularity (32 keys / 8 KB)
constexpr int RS = Hn * Dn; // 2048 floats
constexpr float QSCALE = 0.08838834764831845f * 1.4426950408889634f; // 1/sqrt(D)*log2(e)

// bf16 K/V images, pre-swizzled to the exact LDS chunk layout.
constexpr size_t IMG_BYTES = (size_t)Bn * Hn * 64 * 8192;   // 16 MB each

typedef __bf16 bf16x8 __attribute__((ext_vector_type(8)));
typedef float  f32x16 __attribute__((ext_vector_type(16)));

__device__ __forceinline__ f32x16 mfma32(bf16x8 a, bf16x8 b, f32x16 c) {
  return __builtin_amdgcn_mfma_f32_32x32x16_bf16(a, b, c, 0, 0, 0);
}
__device__ __forceinline__ unsigned pack2(float a, float b) {
  union { __bf16 h[2]; unsigned u; } r;
  r.h[0] = (__bf16)a; r.h[1] = (__bf16)b;
  return r.u;
}
// lane<->lane^32 exchange on the VALU pipe (T12 primitive).
__device__ __forceinline__ float pair_max(float x, int hi) {
  auto r = __builtin_amdgcn_permlane32_swap(__float_as_uint(x), __float_as_uint(x), false, false);
  const float sw = __uint_as_float(hi ? r[0] : r[1]);
  return fmaxf(x, sw);
}
__device__ __forceinline__ float pair_sum(float x, int hi) {
  auto r = __builtin_amdgcn_permlane32_swap(__float_as_uint(x), __float_as_uint(x), false, false);
  const float sw = __uint_as_float(hi ? r[0] : r[1]);
  return x + sw;
}
__device__ __forceinline__ float lane_bcast(int row, float v) {
  return __uint_as_float(__builtin_amdgcn_ds_bpermute(row * 4, __float_as_uint(v)));
}

// async 16B global->LDS DMA (linear dest: uniform lds base + lane*16)
__device__ __forceinline__ void cp16(const char* g, char* l) {
  __builtin_amdgcn_global_load_lds(
      (const __attribute__((address_space(1))) void*)g,
      (__attribute__((address_space(3))) void*)l, 16, 0, 0);
}

// full barrier: DMA'd LDS + ds ops visible to all waves.
__device__ __forceinline__ void dma_barrier() {
  __builtin_amdgcn_sched_barrier(0);
  asm volatile("s_waitcnt vmcnt(0) lgkmcnt(0)" ::: "memory");
  __builtin_amdgcn_s_barrier();
  __builtin_amdgcn_sched_barrier(0);
}

// ============================================================================
// Pre-pass: fp32 K/V -> bf16 images in the EXACT swizzled LDS chunk layout.
// (verbatim R6-R11, verified — R12's "coalesced" prep_v replacement broke
// correctness and is reverted)
// ============================================================================
__global__ __launch_bounds__(256)
void prep_kv(const float* __restrict__ K, const float* __restrict__ V,
             __bf16* __restrict__ KI, __bf16* __restrict__ VI)
{
  const int gid  = (int)blockIdx.x * 256 + (int)threadIdx.x; // 0..2M
  const int half = gid >> 20;              // 0=K, 1=V
  const int id   = gid & ((1 << 20) - 1);  // 0..1M
  const int chunk = id >> 9;               // 0..2047
  const int rem   = id & 511;
  const int bh = chunk >> 6, c = chunk & 63;
  const int b = bh >> 4, h = bh & 15;
  if (half == 0) {
    const int key = rem >> 4, dblk = rem & 15;
    const float* src = K + ((size_t)b * Sn + (size_t)c * 32 + key) * RS + h * Dn + dblk * 8;
    float4 a  = *(const float4*)src;
    float4 c2 = *(const float4*)(src + 4);
    bf16x8 f;
    f[0] = (__bf16)a.x;  f[1] = (__bf16)a.y;  f[2] = (__bf16)a.z;  f[3] = (__bf16)a.w;
    f[4] = (__bf16)c2.x; f[5] = (__bf16)c2.y; f[6] = (__bf16)c2.z; f[7] = (__bf16)c2.w;
    char* dst = (char*)KI + (size_t)chunk * 8192 + ((key * 256 + dblk * 16) ^ ((key & 7) << 4));
    *(bf16x8*)dst = f;
  } else {
    const int d = rem >> 2, koct = rem & 3;
    const float* src = V + ((size_t)b * Sn + (size_t)c * 32 + koct * 8) * RS + h * Dn + d;
    bf16x8 f;
#pragma unroll
    for (int j = 0; j < 8; ++j) f[j] = (__bf16)src[(size_t)j * RS];
    const int off = (d * 64 + koct * 16) ^ ((d & 3) << 4) ^ (((d >> 3) & 1) << 6);
    *(bf16x8*)((char*)VI + (size_t)chunk * 8192 + off) = f;
  }
}

// ============================================================================
// R13 main kernel = R7 verbatim (session best, 97.3 us, verified) + QK8X2:
// the two sub-chunks' 8-deep dependent MFMA chains interleaved for 2-way
// MFMA ILP (pure reordering of independent chains). 256 blocks (1/CU,
// 128 KB LDS) x 512 threads; superstep = 128 keys (4 chunk32s: group 0 ->
// subs 4t,4t+1; group 1 -> 4t+2,4t+3). Block p runs tiles (15-p) then (p):
// every CU = 17 double-supersteps, uniform makespan.
// ============================================================================
__global__ __launch_bounds__(512)
void fa_fwd_dma(const float* __restrict__ Q, const __bf16* __restrict__ KI,
                const __bf16* __restrict__ VI, float* __restrict__ O)
{
  __shared__ __align__(16) __bf16 Klds[8][4096]; // 64 KB, slot = chunk32 & 7
  __shared__ __align__(16) __bf16 Vt[8][4096];   // 64 KB, slot = chunk32 & 7

  const int tid  = threadIdx.x;
  const int lane = tid & 63;
  const int wave = tid >> 6;
  const int col  = lane & 31;
  const int hi   = lane >> 5;
  const int grp  = wave >> 2;   // key-group: subs 4t+2grp, 4t+2grp+1
  const int wq   = wave & 3;

  const int xcd  = (int)blockIdx.x & 7;
  const int s    = (int)blockIdx.x >> 3;    // 0..31
  const int hidx = xcd * 4 + (s & 3);       // 0..31
  const int b    = hidx >> 4, h = hidx & 15;
  const int p    = s >> 2;                  // pair 0..7
  const size_t base = ((size_t)b * Sn) * RS + (size_t)h * Dn;

  const char* KIc = (const char*)KI + (size_t)hidx * 64 * 8192;
  const char* VIc = (const char*)VI + (size_t)hidx * 64 * 8192;

  // per-wave DMA of one 8 KB chunk32 (8x 1 KB rows)
  auto stageKc = [&](int cc) {
    const char* g = KIc + (size_t)cc * 8192 + lane * 16;
    char* l = (char*)&Klds[cc & 7][0];
#pragma unroll
    for (int i = 0; i < 8; ++i) cp16(g + i * 1024, l + i * 1024);
  };
  auto stageVc = [&](int cc) {
    const char* g = VIc + (size_t)cc * 8192 + lane * 16;
    char* l = (char*)&Vt[cc & 7][0];
#pragma unroll
    for (int i = 0; i < 8; ++i) cp16(g + i * 1024, l + i * 1024);
  };

  const int cswz = (col & 7) << 4;
  const int vswz = ((col & 3) << 4) ^ (((col >> 3) & 1) << 6);

#define QK8(kbp, acc) { \
  __builtin_amdgcn_s_setprio(1); \
  _Pragma("unroll") \
  for (int kk = 0; kk < 8; ++kk) { \
    bf16x8 ka = *(const bf16x8*)((kbp) + ((col * 256 + kk * 32 + hi * 16) ^ cswz)); \
    acc = mfma32(ka, qf[kk], acc); \
  } \
  __builtin_amdgcn_s_setprio(0); }

// interleaved dual-chain QK: 2-way MFMA ILP (the chains are independent)
#define QK8X2(kbp0, kbp1, acc0, acc1) { \
  __builtin_amdgcn_s_setprio(1); \
  _Pragma("unroll") \
  for (int kk = 0; kk < 8; ++kk) { \
    bf16x8 ka0 = *(const bf16x8*)((kbp0) + ((col * 256 + kk * 32 + hi * 16) ^ cswz)); \
    bf16x8 ka1 = *(const bf16x8*)((kbp1) + ((col * 256 + kk * 32 + hi * 16) ^ cswz)); \
    acc0 = mfma32(ka0, qf[kk], acc0); \
    acc1 = mfma32(ka1, qf[kk], acc1); \
  } \
  __builtin_amdgcn_s_setprio(0); }

#pragma unroll 1
  for (int tp = 0; tp < 2; ++tp) {
    const int qt  = tp ? p : (15 - p);
    const int q0w = qt * QBLK + wq * 32;
    const int T   = qt + 1;              // supersteps of 128 keys

    // ---- Q fragments, scaled ----
    bf16x8 qf[8];
    {
      const float* qp = Q + base + (size_t)(q0w + col) * RS + hi * 8;
#pragma unroll
      for (int kk = 0; kk < 8; ++kk) {
        float4 a = *(const float4*)(qp + kk * 16);
        float4 c2 = *(const float4*)(qp + kk * 16 + 4);
        bf16x8 f;
        f[0] = (__bf16)(a.x * QSCALE);  f[1] = (__bf16)(a.y * QSCALE);
        f[2] = (__bf16)(a.z * QSCALE);  f[3] = (__bf16)(a.w * QSCALE);
        f[4] = (__bf16)(c2.x * QSCALE); f[5] = (__bf16)(c2.y * QSCALE);
        f[6] = (__bf16)(c2.z * QSCALE); f[7] = (__bf16)(c2.w * QSCALE);
        qf[kk] = f;
      }
    }

    f32x16 o0 = {}, o1 = {}, o2 = {}, o3 = {};
    float m = -1e30f, l = 0.f;

    // ---- prologue: superstep-0 K(0..3)+V(0..3); K(4..7) if T>1 ----
    if (wave < 4) stageKc(wave); else stageVc(wave - 4);
    if (T > 1 && wave < 4) stageKc(4 + wave);
    dma_barrier();

    // S(0): subs cc = 2grp, 2grp+1
    f32x16 sc0 = {}, sc1 = {};
    {
      const int cc = 2 * grp;
      if (cc * 32 <= q0w + 31) {
        const char* kb0 = (const char*)&Klds[cc][0];
        if ((cc + 1) * 32 <= q0w + 31) {
          const char* kb1 = (const char*)&Klds[cc + 1][0];
          QK8X2(kb0, kb1, sc0, sc1)
        } else {
          QK8(kb0, sc0)
        }
      }
    }
    dma_barrier();   // fence S(0) slot 0..3 reads vs iter-0 K DMA (slots 0..3)

#pragma unroll 1
    for (int t = 0; t < T; ++t) {
      // ---- issue next DMAs: K(t+2) -> slots (4t+j)&7 (reads drained at
      // barrier t-1); V(t+1) -> slots (4t+4+j)&7 (disjoint from PV(t)) ----
      if (t + 2 < T && wave < 4) stageKc(4 * (t + 2) + wave);
      if (t + 1 < T && wave >= 4) stageVc(4 * (t + 1) + (wave - 4));

      // ---- QK^T(t+1) on the MFMA pipe ----
      f32x16 sn0 = {}, sn1 = {};
      if (t + 1 < T) {
        const int cc = 4 * (t + 1) + 2 * grp;
        if (cc * 32 <= q0w + 31) {
          const char* kb0 = (const char*)&Klds[cc & 7][0];
          if ((cc + 1) * 32 <= q0w + 31) {
            const char* kb1 = (const char*)&Klds[(cc + 1) & 7][0];
            QK8X2(kb0, kb1, sn0, sn1)
          } else {
            QK8(kb0, sn0)
          }
        }
      }

      // ---- finish superstep t: mask, softmax, repack, PV (2 subs) ----
      const int cc0 = 4 * t + 2 * grp;
      const int kv0 = cc0 * 32;
      if (kv0 <= q0w + 31) {
        const bool v1 = (kv0 + 32) <= q0w + 31;   // wave-uniform

        if (kv0 + 31 > q0w) {
          const int qk = q0w + col - kv0;
#pragma unroll
          for (int r = 0; r < 16; ++r) {
            const int krow = (r & 3) + 8 * (r >> 2) + 4 * hi;
            sc0[r] = (krow <= qk) ? sc0[r] : -1e30f;
          }
        }
        if (v1 && kv0 + 63 > q0w) {
          const int qk1 = q0w + col - (kv0 + 32);
#pragma unroll
          for (int r = 0; r < 16; ++r) {
            const int krow = (r & 3) + 8 * (r >> 2) + 4 * hi;
            sc1[r] = (krow <= qk1) ? sc1[r] : -1e30f;
          }
        }

        float t8[8];
#pragma unroll
        for (int r = 0; r < 8; ++r) t8[r] = fmaxf(sc0[r], sc0[r + 8]);
        if (v1) {
#pragma unroll
          for (int r = 0; r < 8; ++r) t8[r] = fmaxf(t8[r], fmaxf(sc1[r], sc1[r + 8]));
        }
#pragma unroll
        for (int r = 0; r < 4; ++r) t8[r] = fmaxf(t8[r], t8[r + 4]);
        const float pmax = pair_max(fmaxf(fmaxf(t8[0], t8[1]), fmaxf(t8[2], t8[3])), hi);

        if (!__all(pmax <= m + 11.0f)) {   // T13 defer-max
          const float mnew = fmaxf(m, pmax);
          const float al = __builtin_amdgcn_exp2f(m - mnew);
          m = mnew;
          l *= al;
#pragma unroll
          for (int r = 0; r < 16; ++r) {
            const int row = (r & 3) + 8 * (r >> 2) + 4 * hi;
            const float ar = lane_bcast(row, al);
            o0[r] *= ar; o1[r] *= ar; o2[r] *= ar; o3[r] *= ar;
          }
        }

        float s4[4] = {0.f, 0.f, 0.f, 0.f};
#pragma unroll
        for (int r = 0; r < 16; ++r) {
          sc0[r] = __builtin_amdgcn_exp2f(sc0[r] - m);
          s4[r & 3] += sc0[r];
        }
        if (v1) {
#pragma unroll
          for (int r = 0; r < 16; ++r) {
            sc1[r] = __builtin_amdgcn_exp2f(sc1[r] - m);
            s4[r & 3] += sc1[r];
          }
        }
        l += pair_sum((s4[0] + s4[1]) + (s4[2] + s4[3]), hi);

        // P -> A-fragments via permlane32_swap (per sub)
        union { unsigned u[4]; bf16x8 v; } pa0, pa1, pb0, pb1;
        {
          unsigned cw[8];
#pragma unroll
          for (int i = 0; i < 8; ++i) cw[i] = pack2(sc0[2 * i], sc0[2 * i + 1]);
          auto s02 = __builtin_amdgcn_permlane32_swap(cw[0], cw[2], false, false);
          auto s13 = __builtin_amdgcn_permlane32_swap(cw[1], cw[3], false, false);
          auto s46 = __builtin_amdgcn_permlane32_swap(cw[4], cw[6], false, false);
          auto s57 = __builtin_amdgcn_permlane32_swap(cw[5], cw[7], false, false);
          pa0.u[0] = s02[0]; pa0.u[2] = s02[1];
          pa0.u[1] = s13[0]; pa0.u[3] = s13[1];
          pa1.u[0] = s46[0]; pa1.u[2] = s46[1];
          pa1.u[1] = s57[0]; pa1.u[3] = s57[1];
        }
        if (v1) {
          unsigned cw[8];
#pragma unroll
          for (int i = 0; i < 8; ++i) cw[i] = pack2(sc1[2 * i], sc1[2 * i + 1]);
          auto s02 = __builtin_amdgcn_permlane32_swap(cw[0], cw[2], false, false);
          auto s13 = __builtin_amdgcn_permlane32_swap(cw[1], cw[3], false, false);
          auto s46 = __builtin_amdgcn_permlane32_swap(cw[4], cw[6], false, false);
          auto s57 = __builtin_amdgcn_permlane32_swap(cw[5], cw[7], false, false);
          pb0.u[0] = s02[0]; pb0.u[2] = s02[1];
          pb0.u[1] = s13[0]; pb0.u[3] = s13[1];
          pb1.u[0] = s46[0]; pb1.u[2] = s46[1];
          pb1.u[1] = s57[0]; pb1.u[3] = s57[1];
        }

        const char* vb0 = (const char*)&Vt[cc0 & 7][0];
        const char* vb1 = (const char*)&Vt[(cc0 + 1) & 7][0];
        __builtin_amdgcn_s_setprio(1);
#pragma unroll
        for (int ks = 0; ks < 2; ++ks) {
          const bf16x8 pa = ks ? pa1.v : pa0.v;
#define PV_STEP(ovar, dt, vbp) { \
          bf16x8 vf = *(const bf16x8*)((vbp) + ((((dt)*32 + col) * 64 + ks * 32 + hi * 16) ^ vswz)); \
          ovar = mfma32(pa, vf, ovar); }
          PV_STEP(o0, 0, vb0) PV_STEP(o1, 1, vb0) PV_STEP(o2, 2, vb0) PV_STEP(o3, 3, vb0)
        }
        if (v1) {
#pragma unroll
          for (int ks = 0; ks < 2; ++ks) {
            const bf16x8 pa = ks ? pb1.v : pb0.v;
            PV_STEP(o0, 0, vb1) PV_STEP(o1, 1, vb1) PV_STEP(o2, 2, vb1) PV_STEP(o3, 3, vb1)
#undef PV_STEP
          }
        }
        __builtin_amdgcn_s_setprio(0);
      }
      dma_barrier();
      sc0 = sn0; sc1 = sn1;
    }

    // ---- merge group-1 partials into group-0 (LDS scratch over rings) ----
    float* ob  = reinterpret_cast<float*>(&Klds[0][0]);   // 8192 floats (32 KB)
    float* mlb = reinterpret_cast<float*>(&Vt[0][0]);
    if (grp == 1) {
      mlb[wq * 128 + lane] = m;
      mlb[wq * 128 + 64 + lane] = l;
#pragma unroll
      for (int r = 0; r < 16; ++r) {
        ob[wq * 1024 + r * 64 + lane] = o0[r];
        ob[4096 + wq * 1024 + r * 64 + lane] = o1[r];
      }
    }
    __syncthreads();
    float f0 = 1.f, f1 = 0.f;
    if (grp == 0) {
      const float m1 = mlb[wq * 128 + lane];
      const float l1 = mlb[wq * 128 + 64 + lane];
      const float mS = fmaxf(m, m1);
      f0 = __builtin_amdgcn_exp2f(m - mS);
      f1 = __builtin_amdgcn_exp2f(m1 - mS);
      l = l * f0 + l1 * f1;
#pragma unroll
      for (int r = 0; r < 16; ++r) {
        const int row = (r & 3) + 8 * (r >> 2) + 4 * hi;
        const float a0 = lane_bcast(row, f0), a1 = lane_bcast(row, f1);
        o0[r] = o0[r] * a0 + ob[wq * 1024 + r * 64 + lane] * a1;
        o1[r] = o1[r] * a0 + ob[4096 + wq * 1024 + r * 64 + lane] * a1;
      }
    }
    __syncthreads();
    if (grp == 1) {
#pragma unroll
      for (int r = 0; r < 16; ++r) {
        ob[wq * 1024 + r * 64 + lane] = o2[r];
        ob[4096 + wq * 1024 + r * 64 + lane] = o3[r];
      }
    }
    __syncthreads();
    if (grp == 0) {
#pragma unroll
      for (int r = 0; r < 16; ++r) {
        const int row = (r & 3) + 8 * (r >> 2) + 4 * hi;
        const float a0 = lane_bcast(row, f0), a1 = lane_bcast(row, f1);
        o2[r] = o2[r] * a0 + ob[wq * 1024 + r * 64 + lane] * a1;
        o3[r] = o3[r] * a0 + ob[4096 + wq * 1024 + r * 64 + lane] * a1;
      }
      const float linv = 1.0f / l;
#pragma unroll
      for (int r = 0; r < 16; ++r) {
        const int row = (r & 3) + 8 * (r >> 2) + 4 * hi;
        const float lr = lane_bcast(row, linv);
        float* op = O + base + (size_t)(q0w + row) * RS + col;
        op[0]  = o0[r] * lr;
        op[32] = o1[r] * lr;
        op[64] = o2[r] * lr;
        op[96] = o3[r] * lr;
      }
    }
    __syncthreads();   // protect merge scratch before next tile's staging
  }
#undef QK8
#undef QK8X2
}

} // namespace

extern "C" void kernel_launch(void* const* d_in, const int* /*in_sizes*/, int /*n_in*/,
                              void* d_out, int /*out_size*/, void* d_ws, size_t /*ws_size*/,
                              hipStream_t stream) {
  const float* q = (const float*)d_in[0];
  const float* k = (const float*)d_in[1];
  const float* v = (const float*)d_in[2];
  float* o = (float*)d_out;
  // ws >= 32 MB proven on this harness (R6-R11 ran the image path)
  __bf16* ki = (__bf16*)d_ws;
  __bf16* vi = (__bf16*)((char*)d_ws + IMG_BYTES);
  hipLaunchKernelGGL(prep_kv, dim3(8192), dim3(256), 0, stream, k, v, ki, vi);
  hipLaunchKernelGGL(fa_fwd_dma, dim3(256), dim3(512), 0, stream, q, ki, vi, o);
}

// Round 16
// 97.469 us; speedup vs baseline: 1.6344x; 1.0008x over previous
//
#include <hip/hip_runtime.h>
#include <hip/hip_bf16.h>

namespace {

constexpr int Bn = 2, Sn = 2048, Hn = 16, Dn = 128;
constexpr int QBLK = 128;   // 4 q-waves x 32 queries, 2 key-groups
constexpr int KVBLK = 32;   // image chunk granularity (32 keys / 8 KB)
constexpr int RS = Hn * Dn; // 2048 floats
constexpr float QSCALE = 0.08838834764831845f * 1.4426950408889634f; // 1/sqrt(D)*log2(e)

// bf16 K/V images, pre-swizzled to the exact LDS chunk layout.
constexpr size_t IMG_BYTES = (size_t)Bn * Hn * 64 * 8192;   // 16 MB each

typedef __bf16 bf16x8 __attribute__((ext_vector_type(8)));
typedef float  f32x16 __attribute__((ext_vector_type(16)));

__device__ __forceinline__ f32x16 mfma32(bf16x8 a, bf16x8 b, f32x16 c) {
  return __builtin_amdgcn_mfma_f32_32x32x16_bf16(a, b, c, 0, 0, 0);
}
__device__ __forceinline__ unsigned pack2(float a, float b) {
  union { __bf16 h[2]; unsigned u; } r;
  r.h[0] = (__bf16)a; r.h[1] = (__bf16)b;
  return r.u;
}
// lane<->lane^32 exchange on the VALU pipe (T12 primitive).
__device__ __forceinline__ float pair_max(float x, int hi) {
  auto r = __builtin_amdgcn_permlane32_swap(__float_as_uint(x), __float_as_uint(x), false, false);
  const float sw = __uint_as_float(hi ? r[0] : r[1]);
  return fmaxf(x, sw);
}
__device__ __forceinline__ float pair_sum(float x, int hi) {
  auto r = __builtin_amdgcn_permlane32_swap(__float_as_uint(x), __float_as_uint(x), false, false);
  const float sw = __uint_as_float(hi ? r[0] : r[1]);
  return x + sw;
}
__device__ __forceinline__ float lane_bcast(int row, float v) {
  return __uint_as_float(__builtin_amdgcn_ds_bpermute(row * 4, __float_as_uint(v)));
}

// async 16B global->LDS DMA (linear dest: uniform lds base + lane*16)
__device__ __forceinline__ void cp16(const char* g, char* l) {
  __builtin_amdgcn_global_load_lds(
      (const __attribute__((address_space(1))) void*)g,
      (__attribute__((address_space(3))) void*)l, 16, 0, 0);
}

// full barrier: DMA'd LDS + ds ops visible to all waves.
__device__ __forceinline__ void dma_barrier() {
  __builtin_amdgcn_sched_barrier(0);
  asm volatile("s_waitcnt vmcnt(0) lgkmcnt(0)" ::: "memory");
  __builtin_amdgcn_s_barrier();
  __builtin_amdgcn_sched_barrier(0);
}

// ============================================================================
// Pre-pass: fp32 K/V -> bf16 images in the EXACT swizzled LDS chunk layout.
// (verbatim R6-R13, verified)
// ============================================================================
__global__ __launch_bounds__(256)
void prep_kv(const float* __restrict__ K, const float* __restrict__ V,
             __bf16* __restrict__ KI, __bf16* __restrict__ VI)
{
  const int gid  = (int)blockIdx.x * 256 + (int)threadIdx.x; // 0..2M
  const int half = gid >> 20;              // 0=K, 1=V
  const int id   = gid & ((1 << 20) - 1);  // 0..1M
  const int chunk = id >> 9;               // 0..2047
  const int rem   = id & 511;
  const int bh = chunk >> 6, c = chunk & 63;
  const int b = bh >> 4, h = bh & 15;
  if (half == 0) {
    const int key = rem >> 4, dblk = rem & 15;
    const float* src = K + ((size_t)b * Sn + (size_t)c * 32 + key) * RS + h * Dn + dblk * 8;
    float4 a  = *(const float4*)src;
    float4 c2 = *(const float4*)(src + 4);
    bf16x8 f;
    f[0] = (__bf16)a.x;  f[1] = (__bf16)a.y;  f[2] = (__bf16)a.z;  f[3] = (__bf16)a.w;
    f[4] = (__bf16)c2.x; f[5] = (__bf16)c2.y; f[6] = (__bf16)c2.z; f[7] = (__bf16)c2.w;
    char* dst = (char*)KI + (size_t)chunk * 8192 + ((key * 256 + dblk * 16) ^ ((key & 7) << 4));
    *(bf16x8*)dst = f;
  } else {
    const int d = rem >> 2, koct = rem & 3;
    const float* src = V + ((size_t)b * Sn + (size_t)c * 32 + koct * 8) * RS + h * Dn + d;
    bf16x8 f;
#pragma unroll
    for (int j = 0; j < 8; ++j) f[j] = (__bf16)src[(size_t)j * RS];
    const int off = (d * 64 + koct * 16) ^ ((d & 3) << 4) ^ (((d >> 3) & 1) << 6);
    *(bf16x8*)((char*)VI + (size_t)chunk * 8192 + off) = f;
  }
}

// ============================================================================
// Final kernel (R13, verified 97.5 us): R7 structure + QK8X2 dual-chain
// interleave. 256 blocks (1/CU, 128 KB LDS) x 512 threads; superstep =
// 128 keys (4 chunk32s: group 0 -> subs 4t,4t+1; group 1 -> 4t+2,4t+3).
// Block p runs tiles (15-p) then (p): every CU = 17 double-supersteps,
// uniform makespan. K ring-8, V ring-8 by chunk32&7; DMA staged one barrier
// ahead. Session constraint surface (R0-R14): ~8 waves/CU register cap,
// no pipe >25% busy — latency-bound plateau; schedule restructures,
// cross-block merges, and transition-overlap all neutral or broken.
// ============================================================================
__global__ __launch_bounds__(512)
void fa_fwd_dma(const float* __restrict__ Q, const __bf16* __restrict__ KI,
                const __bf16* __restrict__ VI, float* __restrict__ O)
{
  __shared__ __align__(16) __bf16 Klds[8][4096]; // 64 KB, slot = chunk32 & 7
  __shared__ __align__(16) __bf16 Vt[8][4096];   // 64 KB, slot = chunk32 & 7

  const int tid  = threadIdx.x;
  const int lane = tid & 63;
  const int wave = tid >> 6;
  const int col  = lane & 31;
  const int hi   = lane >> 5;
  const int grp  = wave >> 2;   // key-group: subs 4t+2grp, 4t+2grp+1
  const int wq   = wave & 3;

  const int xcd  = (int)blockIdx.x & 7;
  const int s    = (int)blockIdx.x >> 3;    // 0..31
  const int hidx = xcd * 4 + (s & 3);       // 0..31
  const int b    = hidx >> 4, h = hidx & 15;
  const int p    = s >> 2;                  // pair 0..7
  const size_t base = ((size_t)b * Sn) * RS + (size_t)h * Dn;

  const char* KIc = (const char*)KI + (size_t)hidx * 64 * 8192;
  const char* VIc = (const char*)VI + (size_t)hidx * 64 * 8192;

  // per-wave DMA of one 8 KB chunk32 (8x 1 KB rows)
  auto stageKc = [&](int cc) {
    const char* g = KIc + (size_t)cc * 8192 + lane * 16;
    char* l = (char*)&Klds[cc & 7][0];
#pragma unroll
    for (int i = 0; i < 8; ++i) cp16(g + i * 1024, l + i * 1024);
  };
  auto stageVc = [&](int cc) {
    const char* g = VIc + (size_t)cc * 8192 + lane * 16;
    char* l = (char*)&Vt[cc & 7][0];
#pragma unroll
    for (int i = 0; i < 8; ++i) cp16(g + i * 1024, l + i * 1024);
  };

  const int cswz = (col & 7) << 4;
  const int vswz = ((col & 3) << 4) ^ (((col >> 3) & 1) << 6);

#define QK8(kbp, acc) { \
  __builtin_amdgcn_s_setprio(1); \
  _Pragma("unroll") \
  for (int kk = 0; kk < 8; ++kk) { \
    bf16x8 ka = *(const bf16x8*)((kbp) + ((col * 256 + kk * 32 + hi * 16) ^ cswz)); \
    acc = mfma32(ka, qf[kk], acc); \
  } \
  __builtin_amdgcn_s_setprio(0); }

// interleaved dual-chain QK: 2-way MFMA ILP (the chains are independent)
#define QK8X2(kbp0, kbp1, acc0, acc1) { \
  __builtin_amdgcn_s_setprio(1); \
  _Pragma("unroll") \
  for (int kk = 0; kk < 8; ++kk) { \
    bf16x8 ka0 = *(const bf16x8*)((kbp0) + ((col * 256 + kk * 32 + hi * 16) ^ cswz)); \
    bf16x8 ka1 = *(const bf16x8*)((kbp1) + ((col * 256 + kk * 32 + hi * 16) ^ cswz)); \
    acc0 = mfma32(ka0, qf[kk], acc0); \
    acc1 = mfma32(ka1, qf[kk], acc1); \
  } \
  __builtin_amdgcn_s_setprio(0); }

#pragma unroll 1
  for (int tp = 0; tp < 2; ++tp) {
    const int qt  = tp ? p : (15 - p);
    const int q0w = qt * QBLK + wq * 32;
    const int T   = qt + 1;              // supersteps of 128 keys

    // ---- Q fragments, scaled ----
    bf16x8 qf[8];
    {
      const float* qp = Q + base + (size_t)(q0w + col) * RS + hi * 8;
#pragma unroll
      for (int kk = 0; kk < 8; ++kk) {
        float4 a = *(const float4*)(qp + kk * 16);
        float4 c2 = *(const float4*)(qp + kk * 16 + 4);
        bf16x8 f;
        f[0] = (__bf16)(a.x * QSCALE);  f[1] = (__bf16)(a.y * QSCALE);
        f[2] = (__bf16)(a.z * QSCALE);  f[3] = (__bf16)(a.w * QSCALE);
        f[4] = (__bf16)(c2.x * QSCALE); f[5] = (__bf16)(c2.y * QSCALE);
        f[6] = (__bf16)(c2.z * QSCALE); f[7] = (__bf16)(c2.w * QSCALE);
        qf[kk] = f;
      }
    }

    f32x16 o0 = {}, o1 = {}, o2 = {}, o3 = {};
    float m = -1e30f, l = 0.f;

    // ---- prologue: superstep-0 K(0..3)+V(0..3); K(4..7) if T>1 ----
    if (wave < 4) stageKc(wave); else stageVc(wave - 4);
    if (T > 1 && wave < 4) stageKc(4 + wave);
    dma_barrier();

    // S(0): subs cc = 2grp, 2grp+1
    f32x16 sc0 = {}, sc1 = {};
    {
      const int cc = 2 * grp;
      if (cc * 32 <= q0w + 31) {
        const char* kb0 = (const char*)&Klds[cc][0];
        if ((cc + 1) * 32 <= q0w + 31) {
          const char* kb1 = (const char*)&Klds[cc + 1][0];
          QK8X2(kb0, kb1, sc0, sc1)
        } else {
          QK8(kb0, sc0)
        }
      }
    }
    dma_barrier();   // fence S(0) slot 0..3 reads vs iter-0 K DMA (slots 0..3)

#pragma unroll 1
    for (int t = 0; t < T; ++t) {
      // ---- issue next DMAs: K(t+2) -> slots (4t+j)&7 (reads drained at
      // barrier t-1); V(t+1) -> slots (4t+4+j)&7 (disjoint from PV(t)) ----
      if (t + 2 < T && wave < 4) stageKc(4 * (t + 2) + wave);
      if (t + 1 < T && wave >= 4) stageVc(4 * (t + 1) + (wave - 4));

      // ---- QK^T(t+1) on the MFMA pipe ----
      f32x16 sn0 = {}, sn1 = {};
      if (t + 1 < T) {
        const int cc = 4 * (t + 1) + 2 * grp;
        if (cc * 32 <= q0w + 31) {
          const char* kb0 = (const char*)&Klds[cc & 7][0];
          if ((cc + 1) * 32 <= q0w + 31) {
            const char* kb1 = (const char*)&Klds[(cc + 1) & 7][0];
            QK8X2(kb0, kb1, sn0, sn1)
          } else {
            QK8(kb0, sn0)
          }
        }
      }

      // ---- finish superstep t: mask, softmax, repack, PV (2 subs) ----
      const int cc0 = 4 * t + 2 * grp;
      const int kv0 = cc0 * 32;
      if (kv0 <= q0w + 31) {
        const bool v1 = (kv0 + 32) <= q0w + 31;   // wave-uniform

        if (kv0 + 31 > q0w) {
          const int qk = q0w + col - kv0;
#pragma unroll
          for (int r = 0; r < 16; ++r) {
            const int krow = (r & 3) + 8 * (r >> 2) + 4 * hi;
            sc0[r] = (krow <= qk) ? sc0[r] : -1e30f;
          }
        }
        if (v1 && kv0 + 63 > q0w) {
          const int qk1 = q0w + col - (kv0 + 32);
#pragma unroll
          for (int r = 0; r < 16; ++r) {
            const int krow = (r & 3) + 8 * (r >> 2) + 4 * hi;
            sc1[r] = (krow <= qk1) ? sc1[r] : -1e30f;
          }
        }

        float t8[8];
#pragma unroll
        for (int r = 0; r < 8; ++r) t8[r] = fmaxf(sc0[r], sc0[r + 8]);
        if (v1) {
#pragma unroll
          for (int r = 0; r < 8; ++r) t8[r] = fmaxf(t8[r], fmaxf(sc1[r], sc1[r + 8]));
        }
#pragma unroll
        for (int r = 0; r < 4; ++r) t8[r] = fmaxf(t8[r], t8[r + 4]);
        const float pmax = pair_max(fmaxf(fmaxf(t8[0], t8[1]), fmaxf(t8[2], t8[3])), hi);

        if (!__all(pmax <= m + 11.0f)) {   // T13 defer-max
          const float mnew = fmaxf(m, pmax);
          const float al = __builtin_amdgcn_exp2f(m - mnew);
          m = mnew;
          l *= al;
#pragma unroll
          for (int r = 0; r < 16; ++r) {
            const int row = (r & 3) + 8 * (r >> 2) + 4 * hi;
            const float ar = lane_bcast(row, al);
            o0[r] *= ar; o1[r] *= ar; o2[r] *= ar; o3[r] *= ar;
          }
        }

        float s4[4] = {0.f, 0.f, 0.f, 0.f};
#pragma unroll
        for (int r = 0; r < 16; ++r) {
          sc0[r] = __builtin_amdgcn_exp2f(sc0[r] - m);
          s4[r & 3] += sc0[r];
        }
        if (v1) {
#pragma unroll
          for (int r = 0; r < 16; ++r) {
            sc1[r] = __builtin_amdgcn_exp2f(sc1[r] - m);
            s4[r & 3] += sc1[r];
          }
        }
        l += pair_sum((s4[0] + s4[1]) + (s4[2] + s4[3]), hi);

        // P -> A-fragments via permlane32_swap (per sub)
        union { unsigned u[4]; bf16x8 v; } pa0, pa1, pb0, pb1;
        {
          unsigned cw[8];
#pragma unroll
          for (int i = 0; i < 8; ++i) cw[i] = pack2(sc0[2 * i], sc0[2 * i + 1]);
          auto s02 = __builtin_amdgcn_permlane32_swap(cw[0], cw[2], false, false);
          auto s13 = __builtin_amdgcn_permlane32_swap(cw[1], cw[3], false, false);
          auto s46 = __builtin_amdgcn_permlane32_swap(cw[4], cw[6], false, false);
          auto s57 = __builtin_amdgcn_permlane32_swap(cw[5], cw[7], false, false);
          pa0.u[0] = s02[0]; pa0.u[2] = s02[1];
          pa0.u[1] = s13[0]; pa0.u[3] = s13[1];
          pa1.u[0] = s46[0]; pa1.u[2] = s46[1];
          pa1.u[1] = s57[0]; pa1.u[3] = s57[1];
        }
        if (v1) {
          unsigned cw[8];
#pragma unroll
          for (int i = 0; i < 8; ++i) cw[i] = pack2(sc1[2 * i], sc1[2 * i + 1]);
          auto s02 = __builtin_amdgcn_permlane32_swap(cw[0], cw[2], false, false);
          auto s13 = __builtin_amdgcn_permlane32_swap(cw[1], cw[3], false, false);
          auto s46 = __builtin_amdgcn_permlane32_swap(cw[4], cw[6], false, false);
          auto s57 = __builtin_amdgcn_permlane32_swap(cw[5], cw[7], false, false);
          pb0.u[0] = s02[0]; pb0.u[2] = s02[1];
          pb0.u[1] = s13[0]; pb0.u[3] = s13[1];
          pb1.u[0] = s46[0]; pb1.u[2] = s46[1];
          pb1.u[1] = s57[0]; pb1.u[3] = s57[1];
        }

        const char* vb0 = (const char*)&Vt[cc0 & 7][0];
        const char* vb1 = (const char*)&Vt[(cc0 + 1) & 7][0];
        __builtin_amdgcn_s_setprio(1);
#pragma unroll
        for (int ks = 0; ks < 2; ++ks) {
          const bf16x8 pa = ks ? pa1.v : pa0.v;
#define PV_STEP(ovar, dt, vbp) { \
          bf16x8 vf = *(const bf16x8*)((vbp) + ((((dt)*32 + col) * 64 + ks * 32 + hi * 16) ^ vswz)); \
          ovar = mfma32(pa, vf, ovar); }
          PV_STEP(o0, 0, vb0) PV_STEP(o1, 1, vb0) PV_STEP(o2, 2, vb0) PV_STEP(o3, 3, vb0)
        }
        if (v1) {
#pragma unroll
          for (int ks = 0; ks < 2; ++ks) {
            const bf16x8 pa = ks ? pb1.v : pb0.v;
            PV_STEP(o0, 0, vb1) PV_STEP(o1, 1, vb1) PV_STEP(o2, 2, vb1) PV_STEP(o3, 3, vb1)
#undef PV_STEP
          }
        }
        __builtin_amdgcn_s_setprio(0);
      }
      dma_barrier();
      sc0 = sn0; sc1 = sn1;
    }

    // ---- merge group-1 partials into group-0 (LDS scratch over rings) ----
    float* ob  = reinterpret_cast<float*>(&Klds[0][0]);   // 8192 floats (32 KB)
    float* mlb = reinterpret_cast<float*>(&Vt[0][0]);
    if (grp == 1) {
      mlb[wq * 128 + lane] = m;
      mlb[wq * 128 + 64 + lane] = l;
#pragma unroll
      for (int r = 0; r < 16; ++r) {
        ob[wq * 1024 + r * 64 + lane] = o0[r];
        ob[4096 + wq * 1024 + r * 64 + lane] = o1[r];
      }
    }
    __syncthreads();
    float f0 = 1.f, f1 = 0.f;
    if (grp == 0) {
      const float m1 = mlb[wq * 128 + lane];
      const float l1 = mlb[wq * 128 + 64 + lane];
      const float mS = fmaxf(m, m1);
      f0 = __builtin_amdgcn_exp2f(m - mS);
      f1 = __builtin_amdgcn_exp2f(m1 - mS);
      l = l * f0 + l1 * f1;
#pragma unroll
      for (int r = 0; r < 16; ++r) {
        const int row = (r & 3) + 8 * (r >> 2) + 4 * hi;
        const float a0 = lane_bcast(row, f0), a1 = lane_bcast(row, f1);
        o0[r] = o0[r] * a0 + ob[wq * 1024 + r * 64 + lane] * a1;
        o1[r] = o1[r] * a0 + ob[4096 + wq * 1024 + r * 64 + lane] * a1;
      }
    }
    __syncthreads();
    if (grp == 1) {
#pragma unroll
      for (int r = 0; r < 16; ++r) {
        ob[wq * 1024 + r * 64 + lane] = o2[r];
        ob[4096 + wq * 1024 + r * 64 + lane] = o3[r];
      }
    }
    __syncthreads();
    if (grp == 0) {
#pragma unroll
      for (int r = 0; r < 16; ++r) {
        const int row = (r & 3) + 8 * (r >> 2) + 4 * hi;
        const float a0 = lane_bcast(row, f0), a1 = lane_bcast(row, f1);
        o2[r] = o2[r] * a0 + ob[wq * 1024 + r * 64 + lane] * a1;
        o3[r] = o3[r] * a0 + ob[4096 + wq * 1024 + r * 64 + lane] * a1;
      }
      const float linv = 1.0f / l;
#pragma unroll
      for (int r = 0; r < 16; ++r) {
        const int row = (r & 3) + 8 * (r >> 2) + 4 * hi;
        const float lr = lane_bcast(row, linv);
        float* op = O + base + (size_t)(q0w + row) * RS + col;
        op[0]  = o0[r] * lr;
        op[32] = o1[r] * lr;
        op[64] = o2[r] * lr;
        op[96] = o3[r] * lr;
      }
    }
    __syncthreads();   // protect merge scratch before next tile's staging
  }
#undef QK8
#undef QK8X2
}

} // namespace

extern "C" void kernel_launch(void* const* d_in, const int* /*in_sizes*/, int /*n_in*/,
                              void* d_out, int /*out_size*/, void* d_ws, size_t /*ws_size*/,
                              hipStream_t stream) {
  const float* q = (const float*)d_in[0];
  const float* k = (const float*)d_in[1];
  const float* v = (const float*)d_in[2];
  float* o = (float*)d_out;
  // ws >= 32 MB proven on this harness (R6-R13 ran the image path)
  __bf16* ki = (__bf16*)d_ws;
  __bf16* vi = (__bf16*)((char*)d_ws + IMG_BYTES);
  hipLaunchKernelGGL(prep_kv, dim3(8192), dim3(256), 0, stream, k, v, ki, vi);
  hipLaunchKernelGGL(fa_fwd_dma, dim3(256), dim3(512), 0, stream, q, ki, vi, o);
}